// Round 1
// baseline (400.643 us; speedup 1.0000x reference)
//
#include <hip/hip_runtime.h>

#define TGS_D 128
#define TGS_E 20
#define TGS_K 10
#define TGS_F1 (2*TGS_D+TGS_E)   // 276
#define TGS_F2 (3*TGS_D)         // 384
#define ROWS_PER_BLOCK 16

// LEVEL==1: rows are the N*K first-hop neighbors (neighbor table = node_features,
//           gathered via neighbors2; src ids = neighbors1 flat; ts = timestamps[row/K]).
// LEVEL==2: rows are the N source nodes (neighbor table = emb1 rows row*K+k;
//           src ids = source_nodes; ts = timestamps[row]).
template<int LEVEL>
__global__ __launch_bounds__(256)
void tgs_agg_kernel(
    const float* __restrict__ NF,      // node_features [100000,128]
    const float* __restrict__ EF,      // edge_features [500000,20]
    const int*   __restrict__ src_ids,
    const float* __restrict__ ts_arr,  // timestamps [4096]
    const int*   __restrict__ nbr_idx, // LEVEL1: neighbors2 flat; LEVEL2: unused
    const int*   __restrict__ eidx,    // edge idx flat [rows*K]
    const float* __restrict__ etime,   // edge times flat [rows*K]
    const float* __restrict__ emb_in,  // LEVEL2: emb1 [40960,128]
    const float* __restrict__ tw,
    const float* __restrict__ tb,
    const float* __restrict__ W1,      // [276,128] (already offset per layer)
    const float* __restrict__ B1,      // [128]
    const float* __restrict__ W2,      // [384,128]
    const float* __restrict__ B2,      // [128]
    float* __restrict__ out)           // [rows,128]
{
    __shared__ float snf[ROWS_PER_BLOCK][TGS_F1];  // [node(128)|time(128)|edge(20)] summed over K
    __shared__ float sf [ROWS_PER_BLOCK][TGS_F2];  // [src(128)|time0(128)|relu-sum(128)]

    const int d = threadIdx.x & (TGS_D - 1);
    const int g = threadIdx.x >> 7;               // row-group 0/1 (8 rows each)
    const int base_row = blockIdx.x * ROWS_PER_BLOCK;

    const float wd  = tw[d];
    const float bd  = tb[d];
    const float ct0 = __cosf(bd);                 // time_enc(0) = cos(0*w+b)

    // ---------------- phase 0: gather + sum over K neighbors ----------------
    #pragma unroll
    for (int r8 = 0; r8 < 8; ++r8) {
        const int r   = g * 8 + r8;
        const int row = base_row + r;
        const int sid = src_ids[row];
        const float ts = (LEVEL == 1) ? ts_arr[row / TGS_K] : ts_arr[row];

        // neighbor-embedding sum
        float sn = 0.f;
        if (LEVEL == 1) {
            #pragma unroll
            for (int k = 0; k < TGS_K; ++k) {
                const int nb = nbr_idx[row * TGS_K + k];
                sn += NF[nb * TGS_D + d];
            }
        } else {
            #pragma unroll
            for (int k = 0; k < TGS_K; ++k)
                sn += emb_in[(row * TGS_K + k) * TGS_D + d];
        }
        snf[r][d] = sn;

        // edge-time-encoding sum: cos((ts - et)*w + b)
        float st = 0.f;
        #pragma unroll
        for (int k = 0; k < TGS_K; ++k) {
            const float dt = ts - etime[row * TGS_K + k];
            st += __cosf(fmaf(dt, wd, bd));
        }
        snf[r][TGS_D + d] = st;

        // edge-feature sum (first 20 lanes of the 128)
        if (d < TGS_E) {
            float se = 0.f;
            #pragma unroll
            for (int k = 0; k < TGS_K; ++k) {
                const int eb = eidx[row * TGS_K + k];
                se += EF[eb * TGS_E + d];
            }
            snf[r][2 * TGS_D + d] = se;
        }

        // source features + time_enc(0) into sf
        sf[r][d]         = NF[sid * TGS_D + d];
        sf[r][TGS_D + d] = ct0;
    }
    __syncthreads();

    // ---------------- phase 1: GEMV1  relu((Σnf)@W1 + K*b1) ----------------
    {
        float acc[8];
        #pragma unroll
        for (int i = 0; i < 8; ++i) acc[i] = 0.f;

        for (int j = 0; j < TGS_F1; j += 4) {
            const float w0 = W1[(j + 0) * TGS_D + d];
            const float w1 = W1[(j + 1) * TGS_D + d];
            const float w2 = W1[(j + 2) * TGS_D + d];
            const float w3 = W1[(j + 3) * TGS_D + d];
            #pragma unroll
            for (int r8 = 0; r8 < 8; ++r8) {
                const float4 s4 = *(const float4*)&snf[g * 8 + r8][j];
                float a = acc[r8];
                a = fmaf(s4.x, w0, a);
                a = fmaf(s4.y, w1, a);
                a = fmaf(s4.z, w2, a);
                a = fmaf(s4.w, w3, a);
                acc[r8] = a;
            }
        }
        const float b1d = B1[d];
        #pragma unroll
        for (int r8 = 0; r8 < 8; ++r8) {
            const float h = acc[r8] + (float)TGS_K * b1d;
            sf[g * 8 + r8][2 * TGS_D + d] = fmaxf(h, 0.f);
        }
    }
    __syncthreads();

    // ---------------- phase 2: GEMV2  sf@W2 + b2 ----------------
    {
        float acc[8];
        #pragma unroll
        for (int i = 0; i < 8; ++i) acc[i] = 0.f;

        for (int j = 0; j < TGS_F2; j += 4) {
            const float w0 = W2[(j + 0) * TGS_D + d];
            const float w1 = W2[(j + 1) * TGS_D + d];
            const float w2 = W2[(j + 2) * TGS_D + d];
            const float w3 = W2[(j + 3) * TGS_D + d];
            #pragma unroll
            for (int r8 = 0; r8 < 8; ++r8) {
                const float4 s4 = *(const float4*)&sf[g * 8 + r8][j];
                float a = acc[r8];
                a = fmaf(s4.x, w0, a);
                a = fmaf(s4.y, w1, a);
                a = fmaf(s4.z, w2, a);
                a = fmaf(s4.w, w3, a);
                acc[r8] = a;
            }
        }
        const float b2d = B2[d];
        #pragma unroll
        for (int r8 = 0; r8 < 8; ++r8)
            out[(base_row + g * 8 + r8) * TGS_D + d] = acc[r8] + b2d;
    }
}

extern "C" void kernel_launch(void* const* d_in, const int* in_sizes, int n_in,
                              void* d_out, int out_size, void* d_ws, size_t ws_size,
                              hipStream_t stream) {
    const float* NF   = (const float*)d_in[0];
    const float* EF   = (const float*)d_in[1];
    const int*   SRC  = (const int*)  d_in[2];
    const float* TS   = (const float*)d_in[3];
    const int*   NBR1 = (const int*)  d_in[4];
    const int*   EI1  = (const int*)  d_in[5];
    const float* ET1  = (const float*)d_in[6];
    const int*   NBR2 = (const int*)  d_in[7];
    const int*   EI2  = (const int*)  d_in[8];
    const float* ET2  = (const float*)d_in[9];
    const float* TW   = (const float*)d_in[10];
    const float* TB   = (const float*)d_in[11];
    const float* W1   = (const float*)d_in[12];  // [2,276,128]
    const float* B1   = (const float*)d_in[13];  // [2,128]
    const float* W2   = (const float*)d_in[14];  // [2,384,128]
    const float* B2   = (const float*)d_in[15];  // [2,128]

    float* emb1 = (float*)d_ws;                  // [40960,128] fp32 = 20.97 MB

    const int n1 = 4096 * TGS_K;                 // 40960 level-1 rows
    const int n2 = 4096;                         // level-2 rows

    // Level 1: embed the N*K first-hop neighbors (layer-0 weights)
    tgs_agg_kernel<1><<<n1 / ROWS_PER_BLOCK, 256, 0, stream>>>(
        NF, EF, NBR1 /* flat = src ids */, TS, NBR2, EI2, ET2, nullptr,
        TW, TB,
        W1, B1, W2, B2,
        emb1);

    // Level 2: embed the N source nodes (layer-1 weights)
    tgs_agg_kernel<2><<<n2 / ROWS_PER_BLOCK, 256, 0, stream>>>(
        NF, EF, SRC, TS, nullptr, EI1, ET1, emb1,
        TW, TB,
        W1 + TGS_F1 * TGS_D, B1 + TGS_D,
        W2 + TGS_F2 * TGS_D, B2 + TGS_D,
        (float*)d_out);
}

// Round 2
// 222.971 us; speedup vs baseline: 1.7968x; 1.7968x over previous
//
#include <hip/hip_runtime.h>

#define TGS_D 128
#define TGS_E 20
#define TGS_K 10
#define TGS_F1 (2*TGS_D+TGS_E)   // 276
#define RPB 16                   // rows per block

// Precompute tvec[l][d] = B2[l][d] + sum_j cos(tb[j]) * W2[l][128+j][d]
// (the time_enc(0) panel of GEMV2 is row-invariant).
__global__ __launch_bounds__(128)
void tgs_tvec_kernel(const float* __restrict__ tb, const float* __restrict__ W2,
                     const float* __restrict__ B2, float* __restrict__ tvec) {
    const int l = blockIdx.x, d = threadIdx.x;
    const float* w = W2 + l * (3 * TGS_D) * TGS_D + TGS_D * TGS_D;  // middle third
    float acc = B2[l * TGS_D + d];
    for (int j = 0; j < TGS_D; ++j)
        acc = fmaf(__cosf(tb[j]), w[j * TGS_D + d], acc);
    tvec[l * TGS_D + d] = acc;
}

// LEVEL==1: rows = N*K first-hop neighbors (nbr table = node_features via neighbors2,
//           src ids = neighbors1 flat, ts = timestamps[row/K]).
// LEVEL==2: rows = N source nodes (nbr table = emb1 rows row*K+k, src = source_nodes).
template<int LEVEL>
__global__ __launch_bounds__(256, 6)
void tgs_agg_kernel(
    const float* __restrict__ NF,      // node_features [100000,128]
    const float* __restrict__ EF,      // edge_features [500000,20]
    const int*   __restrict__ src_ids,
    const float* __restrict__ ts_arr,  // timestamps [4096]
    const int*   __restrict__ nbr_idx, // LEVEL1: neighbors2 flat
    const int*   __restrict__ eidx,    // edge idx flat [rows*K]
    const float* __restrict__ etime,   // edge times flat [rows*K]
    const float* __restrict__ emb_in,  // LEVEL2: emb1 [40960,128]
    const float* __restrict__ tw,
    const float* __restrict__ tb,
    const float* __restrict__ W1,      // [276,128] (layer-offset)
    const float* __restrict__ B1,      // [128]
    const float* __restrict__ W2,      // [384,128] (layer-offset; middle third unused)
    const float* __restrict__ tvec,    // [128] = B2 + time0 @ W2[128:256]
    float* __restrict__ out)           // [rows,128]
{
    __shared__ float snf[RPB][TGS_F1];  // [nodesum(128)|timesum(128)|edgesum(20)];
                                        // nodesum slot later reused for relu-sum
    __shared__ float sfs[RPB][TGS_D];   // src features

    const int tid = threadIdx.x;
    const int base_row = blockIdx.x * RPB;

    // ---------------- phase 0: gather + sum over K (float4 lanes) ----------------
    {
        const int sub = tid & 31;       // float4 slot within a 128-float row
        const int rr  = tid >> 5;       // 0..7
        const float4 wv = ((const float4*)tw)[sub];
        const float4 bv = ((const float4*)tb)[sub];
        #pragma unroll
        for (int h = 0; h < 2; ++h) {
            const int r   = h * 8 + rr;
            const int row = base_row + r;

            // neighbor-embedding K-sum
            float4 a = make_float4(0.f, 0.f, 0.f, 0.f);
            if (LEVEL == 1) {
                #pragma unroll
                for (int k = 0; k < TGS_K; ++k) {
                    const int nb = nbr_idx[row * TGS_K + k];
                    const float4 v = ((const float4*)(NF + nb * TGS_D))[sub];
                    a.x += v.x; a.y += v.y; a.z += v.z; a.w += v.w;
                }
            } else {
                #pragma unroll
                for (int k = 0; k < TGS_K; ++k) {
                    const float4 v = ((const float4*)(emb_in + (row * TGS_K + k) * TGS_D))[sub];
                    a.x += v.x; a.y += v.y; a.z += v.z; a.w += v.w;
                }
            }
            *(float4*)&snf[r][sub * 4] = a;

            // source features
            const int sid = src_ids[row];
            *(float4*)&sfs[r][sub * 4] = ((const float4*)(NF + sid * TGS_D))[sub];

            // edge-time-encoding K-sum: cos((ts - et)*w + b)
            const float ts = (LEVEL == 1) ? ts_arr[row / TGS_K] : ts_arr[row];
            float4 st = make_float4(0.f, 0.f, 0.f, 0.f);
            #pragma unroll
            for (int k = 0; k < TGS_K; ++k) {
                const float dt = ts - etime[row * TGS_K + k];
                st.x += __cosf(fmaf(dt, wv.x, bv.x));
                st.y += __cosf(fmaf(dt, wv.y, bv.y));
                st.z += __cosf(fmaf(dt, wv.z, bv.z));
                st.w += __cosf(fmaf(dt, wv.w, bv.w));
            }
            *(float4*)&snf[r][TGS_D + sub * 4] = st;

            // edge-feature K-sum (20 floats = 5 float4)
            if (sub < TGS_E / 4) {
                float4 e = make_float4(0.f, 0.f, 0.f, 0.f);
                #pragma unroll
                for (int k = 0; k < TGS_K; ++k) {
                    const int eb = eidx[row * TGS_K + k];
                    const float4 v = ((const float4*)(EF + eb * TGS_E))[sub];
                    e.x += v.x; e.y += v.y; e.z += v.z; e.w += v.w;
                }
                *(float4*)&snf[r][2 * TGS_D + sub * 4] = e;
            }
        }
    }
    __syncthreads();

    const int d = tid & (TGS_D - 1);
    const int g = tid >> 7;             // row-group 0/1 (8 rows each)

    // ---------------- phase 1: GEMV1  relu((sum nf)@W1 + K*b1) ----------------
    {
        float hacc[8];
        #pragma unroll
        for (int i = 0; i < 8; ++i) hacc[i] = 0.f;

        for (int j = 0; j < TGS_F1; j += 4) {
            const float w0 = W1[(j + 0) * TGS_D + d];
            const float w1 = W1[(j + 1) * TGS_D + d];
            const float w2 = W1[(j + 2) * TGS_D + d];
            const float w3 = W1[(j + 3) * TGS_D + d];
            #pragma unroll
            for (int r8 = 0; r8 < 8; ++r8) {
                const float4 s4 = *(const float4*)&snf[g * 8 + r8][j];
                float aa = hacc[r8];
                aa = fmaf(s4.x, w0, aa);
                aa = fmaf(s4.y, w1, aa);
                aa = fmaf(s4.z, w2, aa);
                aa = fmaf(s4.w, w3, aa);
                hacc[r8] = aa;
            }
        }
        __syncthreads();   // all phase-1 reads of snf done before overwrite

        const float b1d = (float)TGS_K * B1[d];
        #pragma unroll
        for (int r8 = 0; r8 < 8; ++r8)
            snf[g * 8 + r8][d] = fmaxf(hacc[r8] + b1d, 0.f);  // reuse nodesum slot
    }
    __syncthreads();

    // ---------------- phase 2: GEMV2  [src|relusum] @ W2[{0:128,256:384}] + tvec ----
    {
        float acc[8];
        #pragma unroll
        for (int i = 0; i < 8; ++i) acc[i] = 0.f;

        for (int j = 0; j < TGS_D; j += 4) {        // src panel
            const float w0 = W2[(j + 0) * TGS_D + d];
            const float w1 = W2[(j + 1) * TGS_D + d];
            const float w2 = W2[(j + 2) * TGS_D + d];
            const float w3 = W2[(j + 3) * TGS_D + d];
            #pragma unroll
            for (int r8 = 0; r8 < 8; ++r8) {
                const float4 s4 = *(const float4*)&sfs[g * 8 + r8][j];
                float aa = acc[r8];
                aa = fmaf(s4.x, w0, aa);
                aa = fmaf(s4.y, w1, aa);
                aa = fmaf(s4.z, w2, aa);
                aa = fmaf(s4.w, w3, aa);
                acc[r8] = aa;
            }
        }
        for (int j = 0; j < TGS_D; j += 4) {        // relu-sum panel
            const float w0 = W2[(2 * TGS_D + j + 0) * TGS_D + d];
            const float w1 = W2[(2 * TGS_D + j + 1) * TGS_D + d];
            const float w2 = W2[(2 * TGS_D + j + 2) * TGS_D + d];
            const float w3 = W2[(2 * TGS_D + j + 3) * TGS_D + d];
            #pragma unroll
            for (int r8 = 0; r8 < 8; ++r8) {
                const float4 s4 = *(const float4*)&snf[g * 8 + r8][j];
                float aa = acc[r8];
                aa = fmaf(s4.x, w0, aa);
                aa = fmaf(s4.y, w1, aa);
                aa = fmaf(s4.z, w2, aa);
                aa = fmaf(s4.w, w3, aa);
                acc[r8] = aa;
            }
        }
        const float tv = tvec[d];
        #pragma unroll
        for (int r8 = 0; r8 < 8; ++r8)
            out[(base_row + g * 8 + r8) * TGS_D + d] = acc[r8] + tv;
    }
}

extern "C" void kernel_launch(void* const* d_in, const int* in_sizes, int n_in,
                              void* d_out, int out_size, void* d_ws, size_t ws_size,
                              hipStream_t stream) {
    const float* NF   = (const float*)d_in[0];
    const float* EF   = (const float*)d_in[1];
    const int*   SRC  = (const int*)  d_in[2];
    const float* TS   = (const float*)d_in[3];
    const int*   NBR1 = (const int*)  d_in[4];
    const int*   EI1  = (const int*)  d_in[5];
    const float* ET1  = (const float*)d_in[6];
    const int*   NBR2 = (const int*)  d_in[7];
    const int*   EI2  = (const int*)  d_in[8];
    const float* ET2  = (const float*)d_in[9];
    const float* TW   = (const float*)d_in[10];
    const float* TB   = (const float*)d_in[11];
    const float* W1   = (const float*)d_in[12];  // [2,276,128]
    const float* B1   = (const float*)d_in[13];  // [2,128]
    const float* W2   = (const float*)d_in[14];  // [2,384,128]
    const float* B2   = (const float*)d_in[15];  // [2,128]

    float* tvec = (float*)d_ws;                  // [2,128]
    float* emb1 = (float*)d_ws + 1024;           // 4 KB offset; [40960,128] fp32

    const int n1 = 4096 * TGS_K;                 // 40960 level-1 rows
    const int n2 = 4096;

    tgs_tvec_kernel<<<2, 128, 0, stream>>>(TB, W2, B2, tvec);

    // Level 1 (layer-0 weights)
    tgs_agg_kernel<1><<<n1 / RPB, 256, 0, stream>>>(
        NF, EF, NBR1, TS, NBR2, EI2, ET2, nullptr,
        TW, TB, W1, B1, W2, tvec, emb1);

    // Level 2 (layer-1 weights)
    tgs_agg_kernel<2><<<n2 / RPB, 256, 0, stream>>>(
        NF, EF, SRC, TS, nullptr, EI1, ET1, emb1,
        TW, TB,
        W1 + TGS_F1 * TGS_D, B1 + TGS_D,
        W2 + 3 * TGS_D * TGS_D, tvec + TGS_D,
        (float*)d_out);
}

// Round 4
// 74.296 us; speedup vs baseline: 5.3925x; 3.0011x over previous
//
#include <hip/hip_runtime.h>

#define TGS_D 128
#define TGS_E 20
#define TGS_K 10
#define TGS_F1 276               // 2D+E
#define LDA1 296                 // f16 stride for A1 panel (pad: bank spread + align)
#define LDA2 264                 // f16 stride for A2 panel
#define RPB 16                   // rows per block (one M-tile)

typedef _Float16 f16;
typedef _Float16 f16x4 __attribute__((ext_vector_type(4)));
typedef _Float16 f16x8 __attribute__((ext_vector_type(8)));
typedef float    f32x4 __attribute__((ext_vector_type(4)));

// ---------------- weight pre-packing (per-fragment layout, k-map = identity) ----
// PW1[((layer*8+ntile)*9+kk)*64 + lane] holds 8 f16: W1[layer][kk*32+(lane>>4)*8+j][ntile*16+(lane&15)]
__global__ void tgs_pack_w1(const float* __restrict__ W1, f16x8* __restrict__ PW1) {
    const int b = blockIdx.x, lane = threadIdx.x;      // grid 2*8*9, block 64
    const int layer = b / 72, rem = b % 72, ntile = rem / 9, kk = rem % 9;
    const int colg = ntile * 16 + (lane & 15);
    const int kbase = kk * 32 + (lane >> 4) * 8;
    f16x8 v;
    #pragma unroll
    for (int j = 0; j < 8; ++j) {
        const int k = kbase + j;
        v[j] = (k < TGS_F1) ? (f16)W1[(layer * TGS_F1 + k) * TGS_D + colg] : (f16)0.f;
    }
    PW1[b * 64 + lane] = v;
}

// A2 logical k: [0:128)=src -> W2 row k ; [128:256)=relusum -> W2 row k+128 (i.e. 256+(k-128))
__global__ void tgs_pack_w2(const float* __restrict__ W2, f16x8* __restrict__ PW2) {
    const int b = blockIdx.x, lane = threadIdx.x;      // grid 2*8*8, block 64
    const int layer = b / 64, rem = b % 64, ntile = rem / 8, kk = rem % 8;
    const int colg = ntile * 16 + (lane & 15);
    const int kbase = kk * 32 + (lane >> 4) * 8;
    f16x8 v;
    #pragma unroll
    for (int j = 0; j < 8; ++j) {
        const int k = kbase + j;
        const int w2row = (k < TGS_D) ? k : (k + TGS_D);
        v[j] = (f16)W2[(layer * 3 * TGS_D + w2row) * TGS_D + colg];
    }
    PW2[b * 64 + lane] = v;
}

// tvec[l][d] = B2[l][d] + sum_j cos(tb[j]) * W2[l][128+j][d]   (time_enc(0) panel)
__global__ __launch_bounds__(128)
void tgs_tvec_kernel(const float* __restrict__ tb, const float* __restrict__ W2,
                     const float* __restrict__ B2, float* __restrict__ tvec) {
    const int l = blockIdx.x, d = threadIdx.x;
    const float* w = W2 + (l * 3 * TGS_D + TGS_D) * TGS_D;
    float acc = B2[l * TGS_D + d];
    for (int j = 0; j < TGS_D; ++j)
        acc = fmaf(__cosf(tb[j]), w[j * TGS_D + d], acc);
    tvec[l * TGS_D + d] = acc;
}

// ---------------- fused per-level kernel: gather+sum -> MFMA GEMM1 -> MFMA GEMM2 ----
template<int LEVEL>
__global__ __launch_bounds__(256, 6)
void tgs_agg_kernel(
    const float* __restrict__ NF, const float* __restrict__ EF,
    const int* __restrict__ src_ids, const float* __restrict__ ts_arr,
    const int* __restrict__ nbr_idx,   // LEVEL1 only
    const int* __restrict__ eidx, const float* __restrict__ etime,
    const float* __restrict__ emb_in,  // LEVEL2 only
    const float* __restrict__ tw, const float* __restrict__ tb,
    const f16x8* __restrict__ PW1, const float* __restrict__ B1,
    const f16x8* __restrict__ PW2, const float* __restrict__ tvec,
    float* __restrict__ out)
{
    __shared__ f16 snf[RPB][LDA1];     // A1: [nodesum 0:128 | timesum 128:256 | edgesum 256:276 | zeroed pad 276:288]
    __shared__ f16 sf2[RPB][LDA2];     // A2: [src 0:128 | relusum 128:256 | pad]
    __shared__ int   s_nbr[RPB * TGS_K];
    __shared__ int   s_eid[RPB * TGS_K];
    __shared__ float s_et [RPB * TGS_K];
    __shared__ float s_ts [RPB];

    const int tid = threadIdx.x;
    const int base_row = blockIdx.x * RPB;

    // ---- stage indices / times (kill 32x-redundant VMEM) ----
    if (tid < RPB * TGS_K) {
        if (LEVEL == 1) s_nbr[tid] = nbr_idx[base_row * TGS_K + tid];
        s_eid[tid] = eidx[base_row * TGS_K + tid];
        s_et [tid] = etime[base_row * TGS_K + tid];
    }
    if (tid < RPB)
        s_ts[tid] = (LEVEL == 1) ? ts_arr[(base_row + tid) / TGS_K] : ts_arr[base_row + tid];
    __syncthreads();

    // ---- phase 0: gather + K-sum (fp32), write f16 panels ----
    {
        const int sub = tid & 31;      // float4 slot within 128
        const int rr  = tid >> 5;      // 0..7
        const float4 wv = ((const float4*)tw)[sub];
        const float4 bv = ((const float4*)tb)[sub];
        #pragma unroll
        for (int h = 0; h < 2; ++h) {
            const int r   = h * 8 + rr;
            const int row = base_row + r;

            // neighbor-embedding K-sum
            float4 a = make_float4(0.f, 0.f, 0.f, 0.f);
            if (LEVEL == 1) {
                #pragma unroll
                for (int k = 0; k < TGS_K; ++k) {
                    const int nb = s_nbr[r * TGS_K + k];
                    const float4 v = ((const float4*)(NF + nb * TGS_D))[sub];
                    a.x += v.x; a.y += v.y; a.z += v.z; a.w += v.w;
                }
            } else {
                #pragma unroll
                for (int k = 0; k < TGS_K; ++k) {
                    const float4 v = ((const float4*)(emb_in + (row * TGS_K + k) * TGS_D))[sub];
                    a.x += v.x; a.y += v.y; a.z += v.z; a.w += v.w;
                }
            }
            *(f16x4*)&snf[r][sub * 4] = f16x4{(f16)a.x, (f16)a.y, (f16)a.z, (f16)a.w};

            // source features
            const int sid = src_ids[row];
            const float4 s = ((const float4*)(NF + sid * TGS_D))[sub];
            *(f16x4*)&sf2[r][sub * 4] = f16x4{(f16)s.x, (f16)s.y, (f16)s.z, (f16)s.w};

            // edge-time-encoding K-sum: cos((ts-et)*w + b)
            const float ts = s_ts[r];
            float4 st = make_float4(0.f, 0.f, 0.f, 0.f);
            #pragma unroll
            for (int k = 0; k < TGS_K; ++k) {
                const float dt = ts - s_et[r * TGS_K + k];
                st.x += __cosf(fmaf(dt, wv.x, bv.x));
                st.y += __cosf(fmaf(dt, wv.y, bv.y));
                st.z += __cosf(fmaf(dt, wv.z, bv.z));
                st.w += __cosf(fmaf(dt, wv.w, bv.w));
            }
            *(f16x4*)&snf[r][TGS_D + sub * 4] = f16x4{(f16)st.x, (f16)st.y, (f16)st.z, (f16)st.w};

            // edge-feature K-sum (20 = 5 float4 slots); lanes 5..7 ZERO the pad
            // [276,288) -- GEMM1's kk=8 step reads it, and leftover LDS bits that
            // alias to f16 NaN/Inf would poison the MFMA row (NaN*0 = NaN).
            if (sub < TGS_E / 4) {
                float4 e = make_float4(0.f, 0.f, 0.f, 0.f);
                #pragma unroll
                for (int k = 0; k < TGS_K; ++k) {
                    const int eb = s_eid[r * TGS_K + k];
                    const float4 v = ((const float4*)(EF + eb * TGS_E))[sub];
                    e.x += v.x; e.y += v.y; e.z += v.z; e.w += v.w;
                }
                *(f16x4*)&snf[r][2 * TGS_D + sub * 4] = f16x4{(f16)e.x, (f16)e.y, (f16)e.z, (f16)e.w};
            } else if (sub < 8) {
                *(f16x4*)&snf[r][2 * TGS_D + sub * 4] =
                    f16x4{(f16)0.f, (f16)0.f, (f16)0.f, (f16)0.f};
            }
        }
    }
    __syncthreads();

    const int lane = tid & 63;
    const int w    = tid >> 6;         // wave id, owns N-tiles 2w, 2w+1
    const int ccol = lane & 15;        // C/D col; also A row for A-frag reads
    const int row0 = (lane >> 4) * 4;  // C/D row base

    // ---- GEMM1: h = relu(A1 @ W1 + 10*b1) -> sf2 relusum panel (f16) ----
    {
        f32x4 acc0 = {0.f, 0.f, 0.f, 0.f}, acc1 = acc0;
        const f16* abase = &snf[lane & 15][(lane >> 4) * 8];
        const int t0 = 2 * w, t1 = 2 * w + 1;
        #pragma unroll
        for (int kk = 0; kk < 9; ++kk) {
            const f16x8 af = *(const f16x8*)(abase + kk * 32);
            const f16x8 b0 = PW1[(t0 * 9 + kk) * 64 + lane];
            const f16x8 b1 = PW1[(t1 * 9 + kk) * 64 + lane];
            acc0 = __builtin_amdgcn_mfma_f32_16x16x32_f16(af, b0, acc0, 0, 0, 0);
            acc1 = __builtin_amdgcn_mfma_f32_16x16x32_f16(af, b1, acc1, 0, 0, 0);
        }
        const float b1v0 = 10.f * B1[t0 * 16 + ccol];
        const float b1v1 = 10.f * B1[t1 * 16 + ccol];
        #pragma unroll
        for (int i = 0; i < 4; ++i) {
            sf2[row0 + i][TGS_D + t0 * 16 + ccol] = (f16)fmaxf(acc0[i] + b1v0, 0.f);
            sf2[row0 + i][TGS_D + t1 * 16 + ccol] = (f16)fmaxf(acc1[i] + b1v1, 0.f);
        }
    }
    __syncthreads();

    // ---- GEMM2: out = A2 @ W2cat + tvec ----
    {
        f32x4 acc0 = {0.f, 0.f, 0.f, 0.f}, acc1 = acc0;
        const f16* abase = &sf2[lane & 15][(lane >> 4) * 8];
        const int t0 = 2 * w, t1 = 2 * w + 1;
        #pragma unroll
        for (int kk = 0; kk < 8; ++kk) {
            const f16x8 af = *(const f16x8*)(abase + kk * 32);
            const f16x8 b0 = PW2[(t0 * 8 + kk) * 64 + lane];
            const f16x8 b1 = PW2[(t1 * 8 + kk) * 64 + lane];
            acc0 = __builtin_amdgcn_mfma_f32_16x16x32_f16(af, b0, acc0, 0, 0, 0);
            acc1 = __builtin_amdgcn_mfma_f32_16x16x32_f16(af, b1, acc1, 0, 0, 0);
        }
        const float tv0 = tvec[t0 * 16 + ccol];
        const float tv1 = tvec[t1 * 16 + ccol];
        #pragma unroll
        for (int i = 0; i < 4; ++i) {
            out[(base_row + row0 + i) * TGS_D + t0 * 16 + ccol] = acc0[i] + tv0;
            out[(base_row + row0 + i) * TGS_D + t1 * 16 + ccol] = acc1[i] + tv1;
        }
    }
}

extern "C" void kernel_launch(void* const* d_in, const int* in_sizes, int n_in,
                              void* d_out, int out_size, void* d_ws, size_t ws_size,
                              hipStream_t stream) {
    const float* NF   = (const float*)d_in[0];
    const float* EF   = (const float*)d_in[1];
    const int*   SRC  = (const int*)  d_in[2];
    const float* TS   = (const float*)d_in[3];
    const int*   NBR1 = (const int*)  d_in[4];
    const int*   EI1  = (const int*)  d_in[5];
    const float* ET1  = (const float*)d_in[6];
    const int*   NBR2 = (const int*)  d_in[7];
    const int*   EI2  = (const int*)  d_in[8];
    const float* ET2  = (const float*)d_in[9];
    const float* TW   = (const float*)d_in[10];
    const float* TB   = (const float*)d_in[11];
    const float* W1   = (const float*)d_in[12];  // [2,276,128]
    const float* B1   = (const float*)d_in[13];  // [2,128]
    const float* W2   = (const float*)d_in[14];  // [2,384,128]
    const float* B2   = (const float*)d_in[15];  // [2,128]

    // workspace layout (16B-aligned offsets)
    float* emb1 = (float*)d_ws;                              // 40960*128*4 = 20,971,520 B
    char*  wsb  = (char*)d_ws + 40960 * TGS_D * 4;
    f16x8* PW1  = (f16x8*)wsb;                               // 2*8*9*64*16  = 147,456 B
    f16x8* PW2  = (f16x8*)(wsb + 147456);                    // 2*8*8*64*16  = 131,072 B
    float* tvec = (float*)(wsb + 147456 + 131072);           // 2*128*4      = 1,024 B

    tgs_pack_w1<<<2 * 8 * 9, 64, 0, stream>>>(W1, PW1);
    tgs_pack_w2<<<2 * 8 * 8, 64, 0, stream>>>(W2, PW2);
    tgs_tvec_kernel<<<2, 128, 0, stream>>>(TB, W2, B2, tvec);

    const int n1 = 4096 * TGS_K;   // 40960 level-1 rows
    const int n2 = 4096;

    // Level 1 (layer-0 weights) -> emb1
    tgs_agg_kernel<1><<<n1 / RPB, 256, 0, stream>>>(
        NF, EF, NBR1, TS, NBR2, EI2, ET2, nullptr,
        TW, TB, PW1, B1, PW2, tvec, emb1);

    // Level 2 (layer-1 weights) -> d_out
    tgs_agg_kernel<2><<<n2 / RPB, 256, 0, stream>>>(
        NF, EF, SRC, TS, nullptr, EI1, ET1, emb1,
        TW, TB,
        PW1 + 8 * 9 * 64, B1 + TGS_D,
        PW2 + 8 * 8 * 64, tvec + TGS_D,
        (float*)d_out);
}